// Round 4
// baseline (505.181 us; speedup 1.0000x reference)
//
#include <hip/hip_runtime.h>
#include <math.h>

// Problem constants
#define M_ROWS 32768   // 32*32*32 positions
#define DIMS   256
#define KCODES 4096
#define NTILE  32      // column tiles of 128
#define EPS_C  0.5f    // collection window vs block-row-min (hh err max ~0.1)
#define EPS_R  1.25f   // refine window (covers EPS_C + f16 key rounding)

// ws layout (float units) — ~2.4 MB
#define WS_CH     0          // 4096*256 halves = 524288 floats (codebook hi f16)
#define WS_V2     524288     // 32768 floats ||v||^2 (fp32-exact)
#define WS_C2     557056     // 4096  floats ||c||^2
#define WS_COLKEY 561152     // 4096  u32 f32-bits colmin (entropy)
#define WS_TOKEN  565248     // 32768 u32 tokens
#define WS_ACC    598016     // 1 float mse_sum
#define WS_CTR    598017     // 1 u32 gather completion counter

// d_out scratch (overwritten by vq_gather at the end):
//   floats [0, 4194304)        : Vh    = 32768*256 f16
//   floats [4194304, 8388608)  : candG = 32768 rows * 32 tiles * 4 u32

typedef _Float16 half8 __attribute__((ext_vector_type(8)));
typedef _Float16 half4 __attribute__((ext_vector_type(4)));
typedef float floatx4 __attribute__((ext_vector_type(4)));

__device__ inline void glds16(const void* g, void* l) {
  __builtin_amdgcn_global_load_lds(
      (const __attribute__((address_space(1))) void*)g,
      (__attribute__((address_space(3))) void*)l, 16, 0, 0);
}

// ---------------------------------------------------------------------------
// prep: f16-hi conversion of V (-> d_out scratch) and CB (-> ws), exact fp32
// norms, plus init of colkey / mse acc / completion counter (replaces memsets).
__global__ __launch_bounds__(256) void vq_prep(const float* __restrict__ V,
                                               const float* __restrict__ CB,
                                               float* __restrict__ ws,
                                               float* __restrict__ outbuf) {
  if (blockIdx.x < 16)
    ((unsigned*)(ws + WS_COLKEY))[blockIdx.x * 256 + threadIdx.x] = 0xFFFFFFFFu;
  if (blockIdx.x == 16 && threadIdx.x == 0) {
    ws[WS_ACC] = 0.f;
    *(unsigned*)(ws + WS_CTR) = 0u;
  }
  int w = threadIdx.x >> 6, lane = threadIdx.x & 63;
  int row = blockIdx.x * 4 + w;
  const float* src;
  _Float16* dst;
  float* nrm;
  if (row < M_ROWS) {
    src = V + (size_t)row * DIMS;
    dst = (_Float16*)outbuf + (size_t)row * DIMS;
    nrm = ws + WS_V2 + row;
  } else {
    int r = row - M_ROWS;
    src = CB + (size_t)r * DIMS;
    dst = (_Float16*)(ws + WS_CH) + (size_t)r * DIMS;
    nrm = ws + WS_C2 + r;
  }
  float4 v = ((const float4*)src)[lane];
  half4 h;
  h[0] = (_Float16)v.x; h[1] = (_Float16)v.y;
  h[2] = (_Float16)v.z; h[3] = (_Float16)v.w;
  *(half4*)(dst + lane * 4) = h;
  float s = v.x * v.x + v.y * v.y + v.z * v.z + v.w * v.w;
  #pragma unroll
  for (int off = 32; off > 0; off >>= 1) s += __shfl_down(s, off, 64);
  if (lane == 0) *nrm = s;
}

// ---------------------------------------------------------------------------
// hh GEMM: 128x128 tile, 4 waves (2x2 of 64x64), glds staging, XOR swizzle.
// 256-thread blocks + launch_bounds(,3) -> 3 blocks/CU (the round-3 512-thread
// version stranded at 1 block/CU and stalled on every barrier drain).
__global__ __launch_bounds__(256, 3) void vq_hh(const _Float16* __restrict__ Vh,
                                                const _Float16* __restrict__ Ch,
                                                const float* __restrict__ wsv2,
                                                const float* __restrict__ wsc2,
                                                unsigned* __restrict__ candG,
                                                unsigned* __restrict__ colkey) {
  __shared__ alignas(16) _Float16 Ah[128 * 32];   // 8 KB
  __shared__ alignas(16) _Float16 Bh[128 * 32];   // 8 KB
  __shared__ float v2s[128];
  __shared__ float c2s[128];
  __shared__ unsigned rowmin[128];
  __shared__ unsigned cnt[128];
  __shared__ unsigned candL[128][4];
  __shared__ float colM[2][128];

  const int t = threadIdx.x;
  const int lane = t & 63, w = t >> 6;
  const int wm = w & 1, wn = w >> 1;          // wave grid 2x2, each 64x64
  const int q = lane >> 4, c = lane & 15;
  const int rt = blockIdx.x >> 5, ct = blockIdx.x & 31;
  const int rowBase = rt * 128, colBase = ct * 128;

  if (t < 128) { v2s[t] = wsv2[rowBase + t]; rowmin[t] = 0xFFFFFFFFu; cnt[t] = 0u; }
  else         c2s[t - 128] = wsc2[colBase + (t - 128)];
  ((unsigned*)candL)[t] = 0xFFFFFFFFu;
  ((unsigned*)candL)[t + 256] = 0xFFFFFFFFu;

  floatx4 acc[4][4];
  #pragma unroll
  for (int i = 0; i < 4; ++i)
    #pragma unroll
    for (int j = 0; j < 4; ++j) acc[i][j] = (floatx4){0.f, 0.f, 0.f, 0.f};

  // staging: 512 16B-chunks per operand, 2 per thread. XOR swizzle:
  // slot (r, jslot) holds k-chunk jslot^((r>>1)&3) of row r.
  const int r0 = t >> 2,               j0 = (t & 3) ^ ((r0 >> 1) & 3);
  const int s1 = t + 256;
  const int r1 = s1 >> 2,              j1 = (s1 & 3) ^ ((r1 >> 1) & 3);
  const _Float16* gA0 = Vh + (size_t)(rowBase + r0) * DIMS + j0 * 8;
  const _Float16* gA1 = Vh + (size_t)(rowBase + r1) * DIMS + j1 * 8;
  const _Float16* gB0 = Ch + (size_t)(colBase + r0) * DIMS + j0 * 8;
  const _Float16* gB1 = Ch + (size_t)(colBase + r1) * DIMS + j1 * 8;
  char* lA0 = (char*)Ah + w * 1024;
  char* lA1 = (char*)Ah + 4096 + w * 1024;
  char* lB0 = (char*)Bh + w * 1024;
  char* lB1 = (char*)Bh + 4096 + w * 1024;
  const int sw = (c >> 1) & 3;                // frag-read swizzle term

  for (int kc = 0; kc < 8; ++kc) {
    __syncthreads();                          // LDS reuse + init cover
    glds16(gA0, lA0); glds16(gA1, lA1);
    glds16(gB0, lB0); glds16(gB1, lB1);
    gA0 += 32; gA1 += 32; gB0 += 32; gB1 += 32;
    __syncthreads();
    half8 a[4], b[4];
    #pragma unroll
    for (int f = 0; f < 4; ++f) {
      int ra = wm * 64 + f * 16 + c;
      int rb = wn * 64 + f * 16 + c;
      a[f] = *(const half8*)(Ah + ra * 32 + (q ^ sw) * 8);
      b[f] = *(const half8*)(Bh + rb * 32 + (q ^ sw) * 8);
    }
    #pragma unroll
    for (int fi = 0; fi < 4; ++fi)
      #pragma unroll
      for (int fj = 0; fj < 4; ++fj)
        acc[fi][fj] = __builtin_amdgcn_mfma_f32_16x16x32_f16(a[fi], b[fj], acc[fi][fj], 0, 0, 0);
  }

  // ---- phase 1: block-row-min + colmin ----
  float cm[4] = {3.4e38f, 3.4e38f, 3.4e38f, 3.4e38f};
  #pragma unroll
  for (int fi = 0; fi < 4; ++fi) {
    #pragma unroll
    for (int r = 0; r < 4; ++r) {
      int ml = wm * 64 + fi * 16 + q * 4 + r;
      float vv = v2s[ml];
      float mn = 3.4e38f;
      #pragma unroll
      for (int fj = 0; fj < 4; ++fj) {
        float d = vv + c2s[wn * 64 + fj * 16 + c] - 2.f * acc[fi][fj][r];
        cm[fj] = fminf(cm[fj], d);
        mn = fminf(mn, d);
      }
      mn = fminf(mn, __shfl_xor(mn, 1, 64));
      mn = fminf(mn, __shfl_xor(mn, 2, 64));
      mn = fminf(mn, __shfl_xor(mn, 4, 64));
      mn = fminf(mn, __shfl_xor(mn, 8, 64));
      if (c == 0) atomicMin(&rowmin[ml], __float_as_uint(mn));
    }
  }
  #pragma unroll
  for (int fj = 0; fj < 4; ++fj) {
    cm[fj] = fminf(cm[fj], __shfl_xor(cm[fj], 16, 64));
    cm[fj] = fminf(cm[fj], __shfl_xor(cm[fj], 32, 64));
  }
  if (lane < 16) {
    #pragma unroll
    for (int fj = 0; fj < 4; ++fj) colM[wm][wn * 64 + fj * 16 + c] = cm[fj];
  }
  __syncthreads();

  // ---- phase 2: collect candidates within rowmin + EPS_C ----
  #pragma unroll
  for (int fi = 0; fi < 4; ++fi) {
    #pragma unroll
    for (int r = 0; r < 4; ++r) {
      int ml = wm * 64 + fi * 16 + q * 4 + r;
      float thresh = __uint_as_float(rowmin[ml]) + EPS_C;
      float vv = v2s[ml];
      #pragma unroll
      for (int fj = 0; fj < 4; ++fj) {
        int nl = wn * 64 + fj * 16 + c;
        float d = vv + c2s[nl] - 2.f * acc[fi][fj][r];
        if (d <= thresh) {
          unsigned pos = atomicAdd(&cnt[ml], 1u);
          if (pos < 4) {
            unsigned short hb = __builtin_bit_cast(unsigned short, (_Float16)d);
            candL[ml][pos] = ((unsigned)hb << 16) | (unsigned)(colBase + nl);
          }
        }
      }
    }
  }
  __syncthreads();
  if (t < 128) {
    *(uint4*)(candG + ((size_t)(rowBase + t) * NTILE + ct) * 4) = *(uint4*)candL[t];
    float cv = fminf(colM[0][t], colM[1][t]);
    atomicMin(&colkey[colBase + t], __float_as_uint(cv));
  }
}

// ---------------------------------------------------------------------------
// refine: per row pick best f16 key; fp64-verify all candidates within EPS_R
// (rare). Separate kernel: must finish reading candG (in d_out) before
// vq_gather overwrites d_out. One wave per row.
__global__ __launch_bounds__(256) void vq_refine(const float* __restrict__ V,
                                                 const float* __restrict__ CB,
                                                 const unsigned* __restrict__ candG,
                                                 unsigned* __restrict__ token) {
  int w = threadIdx.x >> 6, lane = threadIdx.x & 63;
  int row = blockIdx.x * 4 + w;
  const unsigned* cg = candG + (size_t)row * (NTILE * 4);
  unsigned e0 = cg[lane], e1 = cg[lane + 64];
  unsigned m = e0 < e1 ? e0 : e1;
  #pragma unroll
  for (int off = 1; off < 64; off <<= 1) {
    unsigned o = __shfl_xor(m, off, 64);
    m = (o < m) ? o : m;
  }
  float bestv = (float)__builtin_bit_cast(_Float16, (unsigned short)(m >> 16));
  float v0k = (float)__builtin_bit_cast(_Float16, (unsigned short)(e0 >> 16));
  float v1k = (float)__builtin_bit_cast(_Float16, (unsigned short)(e1 >> 16));
  // empty slots (0xFFFF) decode to NaN -> compare false -> excluded
  unsigned long long mask0 = __ballot(v0k <= bestv + EPS_R);
  unsigned long long mask1 = __ballot(v1k <= bestv + EPS_R);
  int tok = (int)(m & 0xFFFFu);
  if (__popcll(mask0) + __popcll(mask1) > 1) {
    float4 x = ((const float4*)(V + (size_t)row * DIMS))[lane];
    double bd = 1e300; int bi = 0x7FFFFFFF;
    #pragma unroll
    for (int h = 0; h < 2; ++h) {
      unsigned long long mask = h ? mask1 : mask0;
      unsigned ee = h ? e1 : e0;
      while (mask) {
        int l = __ffsll((unsigned long long)mask) - 1;
        mask &= mask - 1;
        int idx = (int)(__shfl(ee, l, 64) & 0xFFFFu);
        float4 cv = ((const float4*)(CB + (size_t)idx * DIMS))[lane];
        double dx = (double)cv.x - (double)x.x;
        double dy = (double)cv.y - (double)x.y;
        double dz = (double)cv.z - (double)x.z;
        double dw = (double)cv.w - (double)x.w;
        double s = dx * dx + dy * dy + dz * dz + dw * dw;
        #pragma unroll
        for (int off = 1; off < 64; off <<= 1) s += __shfl_xor(s, off, 64);
        if (s < bd || (s == bd && idx < bi)) { bd = s; bi = idx; }
      }
    }
    tok = bi;
  }
  if (lane == 0) token[row] = (unsigned)tok;
}

// ---------------------------------------------------------------------------
// gather: out = x + (e - x), mse accumulate; the LAST block to finish also
// computes the entropy sum + final loss (fused vq_final).
__global__ __launch_bounds__(256) void vq_gather(const float* __restrict__ V,
                                                 const float* __restrict__ CB,
                                                 const unsigned* __restrict__ token,
                                                 float* __restrict__ ws,
                                                 float* __restrict__ out) {
  __shared__ float psum[4];
  __shared__ int lastFlag;
  int w = threadIdx.x >> 6, lane = threadIdx.x & 63;
  int row = blockIdx.x * 4 + w;
  int tok = (int)token[row];

  float4 e = *(const float4*)(CB + (size_t)tok * DIMS + lane * 4);
  float4 x = *(const float4*)(V + (size_t)row * DIMS + lane * 4);
  float dx = e.x - x.x, dy = e.y - x.y, dz = e.z - x.z, dw = e.w - x.w;
  float4 o;
  o.x = x.x + dx; o.y = x.y + dy; o.z = x.z + dz; o.w = x.w + dw;
  *(float4*)(out + (size_t)row * DIMS + lane * 4) = o;

  float s = dx * dx + dy * dy + dz * dz + dw * dw;
  #pragma unroll
  for (int off = 32; off > 0; off >>= 1) s += __shfl_down(s, off, 64);
  if (lane == 0) psum[w] = s;
  __syncthreads();
  if (threadIdx.x == 0) {
    atomicAdd(&ws[WS_ACC], psum[0] + psum[1] + psum[2] + psum[3]);
    __threadfence();
    unsigned done = atomicAdd((unsigned*)(ws + WS_CTR), 1u);
    lastFlag = (done == (unsigned)(M_ROWS / 4 - 1));
  }
  __syncthreads();
  if (lastFlag) {
    const unsigned* ck = (const unsigned*)(ws + WS_COLKEY);
    float cs = 0.f;
    for (int i = threadIdx.x; i < KCODES; i += 256) cs += __uint_as_float(ck[i]);
    #pragma unroll
    for (int off = 32; off > 0; off >>= 1) cs += __shfl_down(cs, off, 64);
    __syncthreads();
    if (lane == 0) psum[w] = cs;
    __syncthreads();
    if (threadIdx.x == 0) {
      float ent = psum[0] + psum[1] + psum[2] + psum[3];
      // device-scope atomic read of the completed mse sum (L2 not cross-XCD
      // coherent for plain loads within a kernel)
      float msum = atomicAdd(&ws[WS_ACC], 0.f);
      out[8388608] = 1.25f * (msum / 8388608.f) + 0.1f * (ent / 4096.f);
    }
  }
}

// ---------------------------------------------------------------------------
extern "C" void kernel_launch(void* const* d_in, const int* in_sizes, int n_in,
                              void* d_out, int out_size, void* d_ws, size_t ws_size,
                              hipStream_t stream) {
  const float* V  = (const float*)d_in[0];   // [32768, 256]
  const float* CB = (const float*)d_in[1];   // [4096, 256]
  float* out = (float*)d_out;                // 8388608 emb + 1 loss
  float* ws  = (float*)d_ws;

  _Float16* Vh     = (_Float16*)out;                 // scratch in d_out
  unsigned* candG  = (unsigned*)(out + 4194304);     // scratch in d_out (16 MB)
  unsigned* colkey = (unsigned*)(ws + WS_COLKEY);
  unsigned* token  = (unsigned*)(ws + WS_TOKEN);

  vq_prep<<<(M_ROWS + KCODES) / 4, 256, 0, stream>>>(V, CB, ws, out);
  vq_hh<<<8192, 256, 0, stream>>>(Vh, (const _Float16*)(ws + WS_CH),
                                  ws + WS_V2, ws + WS_C2, candG, colkey);
  vq_refine<<<M_ROWS / 4, 256, 0, stream>>>(V, CB, candG, token);
  vq_gather<<<M_ROWS / 4, 256, 0, stream>>>(V, CB, token, ws, out);
}

// Round 5
// 287.443 us; speedup vs baseline: 1.7575x; 1.7575x over previous
//
#include <hip/hip_runtime.h>
#include <math.h>

// Problem constants
#define M_ROWS 32768   // 32*32*32 positions
#define DIMS   256
#define KCODES 4096
#define NTILE  32      // column tiles of 128
#define EPS_C  0.5f    // collection window vs block-row-min (hh err max ~0.1)
#define EPS_R  1.25f   // refine window (covers EPS_C + f16 key rounding)

// ws layout (float units) — ~2.4 MB
#define WS_CH     0          // 4096*256 halves = 524288 floats (codebook hi f16)
#define WS_V2     524288     // 32768 floats ||v||^2 (fp32-exact)
#define WS_C2     557056     // 4096  floats ||c||^2
#define WS_COLKEY 561152     // 4096  u32 f32-bits colmin (entropy)
#define WS_TOKEN  565248     // 32768 u32 tokens
#define WS_PART   598016     // 8192 floats per-block mse partials

// d_out scratch (overwritten by vq_gather at the end):
//   floats [0, 4194304)        : Vh    = 32768*256 f16
//   floats [4194304, 8388608)  : candG = 32768 rows * 32 tiles * 4 u32

typedef _Float16 half8 __attribute__((ext_vector_type(8)));
typedef _Float16 half4 __attribute__((ext_vector_type(4)));
typedef float floatx4 __attribute__((ext_vector_type(4)));

__device__ inline void glds16(const void* g, void* l) {
  __builtin_amdgcn_global_load_lds(
      (const __attribute__((address_space(1))) void*)g,
      (__attribute__((address_space(3))) void*)l, 16, 0, 0);
}

// ---------------------------------------------------------------------------
// prep: f16-hi conversion of V (-> d_out scratch) and CB (-> ws), exact fp32
// norms, plus colkey init (replaces memset).
__global__ __launch_bounds__(256) void vq_prep(const float* __restrict__ V,
                                               const float* __restrict__ CB,
                                               float* __restrict__ ws,
                                               float* __restrict__ outbuf) {
  if (blockIdx.x < 16)
    ((unsigned*)(ws + WS_COLKEY))[blockIdx.x * 256 + threadIdx.x] = 0xFFFFFFFFu;
  int w = threadIdx.x >> 6, lane = threadIdx.x & 63;
  int row = blockIdx.x * 4 + w;
  const float* src;
  _Float16* dst;
  float* nrm;
  if (row < M_ROWS) {
    src = V + (size_t)row * DIMS;
    dst = (_Float16*)outbuf + (size_t)row * DIMS;
    nrm = ws + WS_V2 + row;
  } else {
    int r = row - M_ROWS;
    src = CB + (size_t)r * DIMS;
    dst = (_Float16*)(ws + WS_CH) + (size_t)r * DIMS;
    nrm = ws + WS_C2 + r;
  }
  float4 v = ((const float4*)src)[lane];
  half4 h;
  h[0] = (_Float16)v.x; h[1] = (_Float16)v.y;
  h[2] = (_Float16)v.z; h[3] = (_Float16)v.w;
  *(half4*)(dst + lane * 4) = h;
  float s = v.x * v.x + v.y * v.y + v.z * v.z + v.w * v.w;
  #pragma unroll
  for (int off = 32; off > 0; off >>= 1) s += __shfl_down(s, off, 64);
  if (lane == 0) *nrm = s;
}

// ---------------------------------------------------------------------------
// hh GEMM: 128x128 tile, 4 waves (2x2 of 64x64), glds staging, XOR swizzle,
// 3 blocks/CU. Epilogue: block-row-min + windowed candidate collect + colmin.
__global__ __launch_bounds__(256, 3) void vq_hh(const _Float16* __restrict__ Vh,
                                                const _Float16* __restrict__ Ch,
                                                const float* __restrict__ wsv2,
                                                const float* __restrict__ wsc2,
                                                unsigned* __restrict__ candG,
                                                unsigned* __restrict__ colkey) {
  __shared__ alignas(16) _Float16 Ah[128 * 32];   // 8 KB
  __shared__ alignas(16) _Float16 Bh[128 * 32];   // 8 KB
  __shared__ float v2s[128];
  __shared__ float c2s[128];
  __shared__ unsigned rowmin[128];
  __shared__ unsigned cnt[128];
  __shared__ unsigned candL[128][4];
  __shared__ float colM[2][128];

  const int t = threadIdx.x;
  const int lane = t & 63, w = t >> 6;
  const int wm = w & 1, wn = w >> 1;          // wave grid 2x2, each 64x64
  const int q = lane >> 4, c = lane & 15;
  const int rt = blockIdx.x >> 5, ct = blockIdx.x & 31;
  const int rowBase = rt * 128, colBase = ct * 128;

  if (t < 128) { v2s[t] = wsv2[rowBase + t]; rowmin[t] = 0xFFFFFFFFu; cnt[t] = 0u; }
  else         c2s[t - 128] = wsc2[colBase + (t - 128)];
  ((unsigned*)candL)[t] = 0xFFFFFFFFu;
  ((unsigned*)candL)[t + 256] = 0xFFFFFFFFu;

  floatx4 acc[4][4];
  #pragma unroll
  for (int i = 0; i < 4; ++i)
    #pragma unroll
    for (int j = 0; j < 4; ++j) acc[i][j] = (floatx4){0.f, 0.f, 0.f, 0.f};

  // staging: 512 16B-chunks per operand, 2 per thread. XOR swizzle:
  // slot (r, jslot) holds k-chunk jslot^((r>>1)&3) of row r.
  const int r0 = t >> 2,               j0 = (t & 3) ^ ((r0 >> 1) & 3);
  const int s1 = t + 256;
  const int r1 = s1 >> 2,              j1 = (s1 & 3) ^ ((r1 >> 1) & 3);
  const _Float16* gA0 = Vh + (size_t)(rowBase + r0) * DIMS + j0 * 8;
  const _Float16* gA1 = Vh + (size_t)(rowBase + r1) * DIMS + j1 * 8;
  const _Float16* gB0 = Ch + (size_t)(colBase + r0) * DIMS + j0 * 8;
  const _Float16* gB1 = Ch + (size_t)(colBase + r1) * DIMS + j1 * 8;
  char* lA0 = (char*)Ah + w * 1024;
  char* lA1 = (char*)Ah + 4096 + w * 1024;
  char* lB0 = (char*)Bh + w * 1024;
  char* lB1 = (char*)Bh + 4096 + w * 1024;
  const int sw = (c >> 1) & 3;                // frag-read swizzle term

  for (int kc = 0; kc < 8; ++kc) {
    __syncthreads();                          // LDS reuse + init cover
    glds16(gA0, lA0); glds16(gA1, lA1);
    glds16(gB0, lB0); glds16(gB1, lB1);
    gA0 += 32; gA1 += 32; gB0 += 32; gB1 += 32;
    __syncthreads();
    half8 a[4], b[4];
    #pragma unroll
    for (int f = 0; f < 4; ++f) {
      int ra = wm * 64 + f * 16 + c;
      int rb = wn * 64 + f * 16 + c;
      a[f] = *(const half8*)(Ah + ra * 32 + (q ^ sw) * 8);
      b[f] = *(const half8*)(Bh + rb * 32 + (q ^ sw) * 8);
    }
    #pragma unroll
    for (int fi = 0; fi < 4; ++fi)
      #pragma unroll
      for (int fj = 0; fj < 4; ++fj)
        acc[fi][fj] = __builtin_amdgcn_mfma_f32_16x16x32_f16(a[fi], b[fj], acc[fi][fj], 0, 0, 0);
  }

  // ---- phase 1: block-row-min + colmin ----
  float cm[4] = {3.4e38f, 3.4e38f, 3.4e38f, 3.4e38f};
  #pragma unroll
  for (int fi = 0; fi < 4; ++fi) {
    #pragma unroll
    for (int r = 0; r < 4; ++r) {
      int ml = wm * 64 + fi * 16 + q * 4 + r;
      float vv = v2s[ml];
      float mn = 3.4e38f;
      #pragma unroll
      for (int fj = 0; fj < 4; ++fj) {
        float d = vv + c2s[wn * 64 + fj * 16 + c] - 2.f * acc[fi][fj][r];
        cm[fj] = fminf(cm[fj], d);
        mn = fminf(mn, d);
      }
      mn = fminf(mn, __shfl_xor(mn, 1, 64));
      mn = fminf(mn, __shfl_xor(mn, 2, 64));
      mn = fminf(mn, __shfl_xor(mn, 4, 64));
      mn = fminf(mn, __shfl_xor(mn, 8, 64));
      if (c == 0) atomicMin(&rowmin[ml], __float_as_uint(mn));
    }
  }
  #pragma unroll
  for (int fj = 0; fj < 4; ++fj) {
    cm[fj] = fminf(cm[fj], __shfl_xor(cm[fj], 16, 64));
    cm[fj] = fminf(cm[fj], __shfl_xor(cm[fj], 32, 64));
  }
  if (lane < 16) {
    #pragma unroll
    for (int fj = 0; fj < 4; ++fj) colM[wm][wn * 64 + fj * 16 + c] = cm[fj];
  }
  __syncthreads();

  // ---- phase 2: collect candidates within rowmin + EPS_C ----
  #pragma unroll
  for (int fi = 0; fi < 4; ++fi) {
    #pragma unroll
    for (int r = 0; r < 4; ++r) {
      int ml = wm * 64 + fi * 16 + q * 4 + r;
      float thresh = __uint_as_float(rowmin[ml]) + EPS_C;
      float vv = v2s[ml];
      #pragma unroll
      for (int fj = 0; fj < 4; ++fj) {
        int nl = wn * 64 + fj * 16 + c;
        float d = vv + c2s[nl] - 2.f * acc[fi][fj][r];
        if (d <= thresh) {
          unsigned pos = atomicAdd(&cnt[ml], 1u);
          if (pos < 4) {
            unsigned short hb = __builtin_bit_cast(unsigned short, (_Float16)d);
            candL[ml][pos] = ((unsigned)hb << 16) | (unsigned)(colBase + nl);
          }
        }
      }
    }
  }
  __syncthreads();
  if (t < 128) {
    *(uint4*)(candG + ((size_t)(rowBase + t) * NTILE + ct) * 4) = *(uint4*)candL[t];
    float cv = fminf(colM[0][t], colM[1][t]);
    atomicMin(&colkey[colBase + t], __float_as_uint(cv));
  }
}

// ---------------------------------------------------------------------------
// refine: per row pick best f16 key; fp64-verify all candidates within EPS_R
// (rare). Separate kernel: must finish reading candG (in d_out) before
// vq_gather overwrites d_out. One wave per row.
__global__ __launch_bounds__(256) void vq_refine(const float* __restrict__ V,
                                                 const float* __restrict__ CB,
                                                 const unsigned* __restrict__ candG,
                                                 unsigned* __restrict__ token) {
  int w = threadIdx.x >> 6, lane = threadIdx.x & 63;
  int row = blockIdx.x * 4 + w;
  const unsigned* cg = candG + (size_t)row * (NTILE * 4);
  unsigned e0 = cg[lane], e1 = cg[lane + 64];
  unsigned m = e0 < e1 ? e0 : e1;
  #pragma unroll
  for (int off = 1; off < 64; off <<= 1) {
    unsigned o = __shfl_xor(m, off, 64);
    m = (o < m) ? o : m;
  }
  float bestv = (float)__builtin_bit_cast(_Float16, (unsigned short)(m >> 16));
  float v0k = (float)__builtin_bit_cast(_Float16, (unsigned short)(e0 >> 16));
  float v1k = (float)__builtin_bit_cast(_Float16, (unsigned short)(e1 >> 16));
  // empty slots (0xFFFF) decode to NaN -> compare false -> excluded
  unsigned long long mask0 = __ballot(v0k <= bestv + EPS_R);
  unsigned long long mask1 = __ballot(v1k <= bestv + EPS_R);
  int tok = (int)(m & 0xFFFFu);
  if (__popcll(mask0) + __popcll(mask1) > 1) {
    float4 x = ((const float4*)(V + (size_t)row * DIMS))[lane];
    double bd = 1e300; int bi = 0x7FFFFFFF;
    #pragma unroll
    for (int h = 0; h < 2; ++h) {
      unsigned long long mask = h ? mask1 : mask0;
      unsigned ee = h ? e1 : e0;
      while (mask) {
        int l = __ffsll((unsigned long long)mask) - 1;
        mask &= mask - 1;
        int idx = (int)(__shfl(ee, l, 64) & 0xFFFFu);
        float4 cv = ((const float4*)(CB + (size_t)idx * DIMS))[lane];
        double dx = (double)cv.x - (double)x.x;
        double dy = (double)cv.y - (double)x.y;
        double dz = (double)cv.z - (double)x.z;
        double dw = (double)cv.w - (double)x.w;
        double s = dx * dx + dy * dy + dz * dz + dw * dw;
        #pragma unroll
        for (int off = 1; off < 64; off <<= 1) s += __shfl_xor(s, off, 64);
        if (s < bd || (s == bd && idx < bi)) { bd = s; bi = idx; }
      }
    }
    tok = bi;
  }
  if (lane == 0) token[row] = (unsigned)tok;
}

// ---------------------------------------------------------------------------
// gather: out = x + (e - x); per-block mse partial via PLAIN STORE (round 4's
// __threadfence per block forced an L2 wb/inv per block -> 268 us stall).
__global__ __launch_bounds__(256) void vq_gather(const float* __restrict__ V,
                                                 const float* __restrict__ CB,
                                                 const unsigned* __restrict__ token,
                                                 float* __restrict__ ws,
                                                 float* __restrict__ out) {
  __shared__ float psum[4];
  int w = threadIdx.x >> 6, lane = threadIdx.x & 63;
  int row = blockIdx.x * 4 + w;
  int tok = (int)token[row];

  float4 e = *(const float4*)(CB + (size_t)tok * DIMS + lane * 4);
  float4 x = *(const float4*)(V + (size_t)row * DIMS + lane * 4);
  float dx = e.x - x.x, dy = e.y - x.y, dz = e.z - x.z, dw = e.w - x.w;
  float4 o;
  o.x = x.x + dx; o.y = x.y + dy; o.z = x.z + dz; o.w = x.w + dw;
  *(float4*)(out + (size_t)row * DIMS + lane * 4) = o;

  float s = dx * dx + dy * dy + dz * dz + dw * dw;
  #pragma unroll
  for (int off = 32; off > 0; off >>= 1) s += __shfl_down(s, off, 64);
  if (lane == 0) psum[w] = s;
  __syncthreads();
  if (threadIdx.x == 0)
    ws[WS_PART + blockIdx.x] = psum[0] + psum[1] + psum[2] + psum[3];
}

// ---------------------------------------------------------------------------
// final: sum 8192 mse partials + 4096 colmins, write loss. One block.
__global__ __launch_bounds__(256) void vq_final(const float* __restrict__ ws,
                                                float* __restrict__ out) {
  __shared__ float psum[4];
  float s = 0.f;
  for (int i = threadIdx.x; i < 8192; i += 256) s += ws[WS_PART + i];
  const unsigned* ck = (const unsigned*)(ws + WS_COLKEY);
  float cs = 0.f;
  for (int i = threadIdx.x; i < KCODES; i += 256) cs += __uint_as_float(ck[i]);
  float v = s * (1.25f / 8388608.f) + cs * (0.1f / 4096.f);
  #pragma unroll
  for (int off = 32; off > 0; off >>= 1) v += __shfl_down(v, off, 64);
  int w = threadIdx.x >> 6, lane = threadIdx.x & 63;
  if (lane == 0) psum[w] = v;
  __syncthreads();
  if (threadIdx.x == 0)
    out[8388608] = psum[0] + psum[1] + psum[2] + psum[3];
}

// ---------------------------------------------------------------------------
extern "C" void kernel_launch(void* const* d_in, const int* in_sizes, int n_in,
                              void* d_out, int out_size, void* d_ws, size_t ws_size,
                              hipStream_t stream) {
  const float* V  = (const float*)d_in[0];   // [32768, 256]
  const float* CB = (const float*)d_in[1];   // [4096, 256]
  float* out = (float*)d_out;                // 8388608 emb + 1 loss
  float* ws  = (float*)d_ws;

  _Float16* Vh     = (_Float16*)out;                 // scratch in d_out
  unsigned* candG  = (unsigned*)(out + 4194304);     // scratch in d_out (16 MB)
  unsigned* colkey = (unsigned*)(ws + WS_COLKEY);
  unsigned* token  = (unsigned*)(ws + WS_TOKEN);

  vq_prep<<<(M_ROWS + KCODES) / 4, 256, 0, stream>>>(V, CB, ws, out);
  vq_hh<<<8192, 256, 0, stream>>>(Vh, (const _Float16*)(ws + WS_CH),
                                  ws + WS_V2, ws + WS_C2, candG, colkey);
  vq_refine<<<M_ROWS / 4, 256, 0, stream>>>(V, CB, candG, token);
  vq_gather<<<M_ROWS / 4, 256, 0, stream>>>(V, CB, token, ws, out);
  vq_final<<<1, 256, 0, stream>>>(ws, out);
}